// Round 8
// baseline (622.005 us; speedup 1.0000x reference)
//
#include <hip/hip_runtime.h>
#include <cstdint>

// GRU (B=128, T=128, I=12, H=512) persistent kernel, round 8.
// 256 WGs = 8 batch-groups (16 rows) x 32 col-groups (16 h-cols), 1 WG/CU.
// W_hh chunk LDS-resident in MFMA fragment order (bf16 hi/lo x3 MFMA).
// Round-7 base: self-tagged exchange (u32 = hi16|lo14|tag2), sc1 ops, no
// per-step flags/drains. Round-8: (1) selective-retry poll with s_sleep
// backoff (only re-read mismatched dwordx4 chunks — kills L3 poll storm);
// (2) per-wave decoupling: each wave polls/stages only its K-quarter
// (cols [128w,128w+128) = its MFMA A range = written only by it), starts
// MFMA without waiting for other quarters. Single pre-gates __syncthreads
// joins waves (this barrier is also what keeps the tag-slot protocol's
// consumption-ordering proof valid — do not remove).

typedef __attribute__((ext_vector_type(4))) float f32x4;
typedef __attribute__((ext_vector_type(8))) __bf16 bf16x8;

#define NTHREADS 256
#define CG_N 32
#define BB 16
#define HC 16
#define T_STEPS 128
#define I_DIM 12
#define H_DIM 512

// ws byte offsets
#define WS_HX0   0         // hx[0]: [128][512] u32   256 KB
#define WS_HX1   262144    // hx[1]                   256 KB
#define WS_FLAGS 524288    // [8 bg][32 consumer][32 producer] u32 (init barrier only)

__device__ __forceinline__ float bf16f(unsigned short u){
  return __uint_as_float(((unsigned int)u) << 16);
}
__device__ __forceinline__ void split_bf16(float x, unsigned short &hi, unsigned short &lo){
  unsigned int u = __float_as_uint(x);
  hi = (unsigned short)(u >> 16);
  float r = x - __uint_as_float((u >> 16) << 16);   // exact residual
  unsigned int ru = __float_as_uint(r);
  ru += 0x7fffu + ((ru >> 16) & 1u);                // RNE to bf16
  lo = (unsigned short)(ru >> 16);
}
__device__ __forceinline__ float fsigmoid(float x){ return 1.0f / (1.0f + __expf(-x)); }
__device__ __forceinline__ float ftanh(float x){ return 2.0f / (1.0f + __expf(-2.0f * x)) - 1.0f; }
__device__ __forceinline__ f32x4 MFMA(bf16x8 a, bf16x8 b, f32x4 c){
  return __builtin_amdgcn_mfma_f32_16x16x32_bf16(a, b, c, 0, 0, 0);
}
__device__ __forceinline__ void wait_vm0(){
  asm volatile("s_waitcnt vmcnt(0)" ::: "memory");
}
__device__ __forceinline__ unsigned int hiP(unsigned int x, unsigned int y){
  return (x >> 16) | (y & 0xFFFF0000u);
}
__device__ __forceinline__ unsigned int loP(unsigned int x, unsigned int y){
  return (x & 0xFFFFu) | (y << 16);
}

// sc1 (device-scope) primitives — proven r3/r4/r7 exchange path
__device__ __forceinline__ void dev_store_u32(unsigned int* p, unsigned int v){
  asm volatile("global_store_dword %0, %1, off sc1" :: "v"(p), "v"(v) : "memory");
}
__device__ __forceinline__ unsigned int dev_load_u32(const unsigned int* p){
  unsigned int v;
  asm volatile("global_load_dword %0, %1, off sc1\n\ts_waitcnt vmcnt(0)"
               : "=v"(v) : "v"(p) : "memory");
  return v;
}
__device__ __forceinline__ uint4 load4_sc1(const unsigned int* p){
  uint4 v;
  asm volatile("global_load_dwordx4 %0, %1, off sc1" : "=v"(v) : "v"(p) : "memory");
  return v;
}
__device__ __forceinline__ void load_h_row(const unsigned int* p, uint4* pr){
  uint4 v0, v1, v2, v3, v4, v5, v6, v7;
  asm volatile(
    "global_load_dwordx4 %0, %8, off sc1\n\t"
    "global_load_dwordx4 %1, %8, off offset:16 sc1\n\t"
    "global_load_dwordx4 %2, %8, off offset:32 sc1\n\t"
    "global_load_dwordx4 %3, %8, off offset:48 sc1\n\t"
    "global_load_dwordx4 %4, %8, off offset:64 sc1\n\t"
    "global_load_dwordx4 %5, %8, off offset:80 sc1\n\t"
    "global_load_dwordx4 %6, %8, off offset:96 sc1\n\t"
    "global_load_dwordx4 %7, %8, off offset:112 sc1\n\t"
    "s_waitcnt vmcnt(0)"
    : "=&v"(v0), "=&v"(v1), "=&v"(v2), "=&v"(v3),
      "=&v"(v4), "=&v"(v5), "=&v"(v6), "=&v"(v7)
    : "v"(p) : "memory");
  pr[0]=v0; pr[1]=v1; pr[2]=v2; pr[3]=v3; pr[4]=v4; pr[5]=v5; pr[6]=v6; pr[7]=v7;
}

__device__ __forceinline__ bool tag_bad(const uint4& v, unsigned int want){
  return ((((v.x ^ want) | (v.y ^ want)) | ((v.z ^ want) | (v.w ^ want))) & 3u) != 0u;
}

// poll until all 32 u32 carry tag `want`: full sweep once, then selective
// retries (only mismatched chunks) with s_sleep backoff.
__device__ __forceinline__ void poll_h_row(const unsigned int* p, uint4* pr,
                                           unsigned int want){
  load_h_row(p, pr);
  unsigned int pend = 0u;
  #pragma unroll
  for (int b = 0; b < 8; ++b)
    if (tag_bad(pr[b], want)) pend |= (1u << b);
  while (pend){
    __builtin_amdgcn_s_sleep(1);
    #pragma unroll
    for (int b = 0; b < 8; ++b)
      if (pend & (1u << b)) pr[b] = load4_sc1(p + b*4);
    wait_vm0();
    #pragma unroll
    for (int b = 0; b < 8; ++b)
      if ((pend & (1u << b)) && !tag_bad(pr[b], want)) pend &= ~(1u << b);
  }
  #pragma unroll
  for (int b = 0; b < 8; ++b){
    pr[b].x &= 0xFFFFFFFCu; pr[b].y &= 0xFFFFFFFCu;
    pr[b].z &= 0xFFFFFFFCu; pr[b].w &= 0xFFFFFFFCu;
  }
}

extern "C" __global__ void __launch_bounds__(NTHREADS, 1)
gru_persistent(const float* __restrict__ hist, const float* __restrict__ wih,
               const float* __restrict__ whh, const float* __restrict__ wpred,
               float* __restrict__ out, unsigned char* __restrict__ ws)
{
  __shared__ __align__(16) unsigned short whi_l[3*16*64*8];   // 49152 B
  __shared__ __align__(16) unsigned short wlo_l[3*16*64*8];   // 49152 B
  __shared__ __align__(16) unsigned short hhi_l[BB*H_DIM];    // 16384 B (swizzled)
  __shared__ __align__(16) unsigned short hlo_l[BB*H_DIM];    // 16384 B (swizzled)
  __shared__ __align__(16) float part_l[4*3*64*4];            // 12288 B
  __shared__ __align__(16) float x_l[BB*I_DIM];               // 768 B
  __shared__ __align__(16) float wih_l[48*I_DIM];             // 2304 B
  __shared__ __align__(16) float wpred_l[2*H_DIM];            // 4096 B (cg<4 only)

  const int tid  = threadIdx.x;
  const int bg   = blockIdx.x & 7;
  const int cg   = blockIdx.x >> 3;
  const int wave = tid >> 6;
  const int lane = tid & 63;

  unsigned int* hx[2] = {(unsigned int*)(ws + WS_HX0), (unsigned int*)(ws + WS_HX1)};
  unsigned int* flagsP = (unsigned int*)(ws + WS_FLAGS);

  // ---- Prologue: stage W_ih / W_pred, convert W_hh chunk to LDS fragments ----
  for (int i = tid; i < 48*I_DIM; i += NTHREADS){
    int j = i / I_DIM, ii = i % I_DIM;
    int R = (j >> 4)*H_DIM + cg*HC + (j & 15);      // gate-major rows: r,z,n
    wih_l[i] = wih[R*I_DIM + ii];
  }
  if (cg < 4){
    for (int i = tid; i < 2*H_DIM; i += NTHREADS) wpred_l[i] = wpred[i];
  }
  #pragma unroll
  for (int it = 0; it < 24; ++it){
    int f0 = (it*NTHREADS + tid) * 4;               // flat [48*512], k-aligned 4
    int j = f0 >> 9, k = f0 & 511;
    int R = (j >> 4)*H_DIM + cg*HC + (j & 15);
    float4 v = *(const float4*)(whh + R*H_DIM + k);
    int nt = j >> 4;
    int ln = (j & 15) | (((k >> 3) & 3) << 4);
    int kt = k >> 5, e = k & 7;
    int base = (((nt*16 + kt)*64) + ln)*8 + e;      // half index
    float vv[4] = {v.x, v.y, v.z, v.w};
    unsigned short h4[4], l4[4];
    #pragma unroll
    for (int q = 0; q < 4; ++q) split_bf16(vv[q], h4[q], l4[q]);
    uint2 uh, ul;
    uh.x = (unsigned int)h4[0] | ((unsigned int)h4[1] << 16);
    uh.y = (unsigned int)h4[2] | ((unsigned int)h4[3] << 16);
    ul.x = (unsigned int)l4[0] | ((unsigned int)l4[1] << 16);
    ul.y = (unsigned int)l4[2] | ((unsigned int)l4[3] << 16);
    *(uint2*)((char*)whi_l + base*2) = uh;
    *(uint2*)((char*)wlo_l + base*2) = ul;
  }

  // ---- init: rewrite BOTH slots (erase replay-stale tags), then one
  //      sc1 flag barrier (prevents step-0 stale-tag-0 reads). ----
  {
    int b = tid >> 4, hc = tid & 15;
    int gidx = (bg*BB + b)*H_DIM + cg*HC + hc;
    dev_store_u32(hx[0] + gidx, 0u);   // h0=0, tag=0
    dev_store_u32(hx[1] + gidx, 2u);   // payload irrelevant, tag=2
  }
  wait_vm0();
  __syncthreads();
  if (wave == 0 && lane < CG_N)
    dev_store_u32(flagsP + (bg*CG_N + lane)*CG_N + cg, 1u);
  if (wave == 0){
    const unsigned int* fp = flagsP + (bg*CG_N + cg)*CG_N + (lane & 31);
    for (;;){
      unsigned int f = dev_load_u32(fp);
      if (__ballot(f >= 1u) == ~0ull) break;
      __builtin_amdgcn_s_sleep(1);
    }
  }
  __syncthreads();

  // ---- main recurrence: no per-step barrier before MFMA; waves decoupled ----
  for (int t = 0; t < T_STEPS; ++t){
    const int cur = t & 1, nxt = cur ^ 1;

    if (tid < BB*I_DIM){
      int b = tid / I_DIM, ii = tid % I_DIM;
      x_l[tid] = hist[((bg*BB + b)*T_STEPS + t)*I_DIM + ii];
    }

    // Phase 1 (per-wave): poll own K-quarter -> unpack -> swizzled LDS.
    // Thread covers row=tid&15, cols [(tid>>4)*32,+32) — wave w's threads
    // cover exactly cols [128w,128w+128) = the A-range of its MFMAs.
    {
      int row = tid & 15, col0 = (tid >> 4) * 32;
      const unsigned int* p = hx[cur] + (bg*BB + row)*H_DIM + col0;
      uint4 pr[8];
      poll_h_row(p, pr, (unsigned int)(t & 3));
      #pragma unroll
      for (int k = 0; k < 4; ++k){
        uint4 a = pr[2*k], b = pr[2*k+1];
        uint4 hi4 = { hiP(a.x,a.y), hiP(a.z,a.w), hiP(b.x,b.y), hiP(b.z,b.w) };
        uint4 lo4 = { loP(a.x,a.y), loP(a.z,a.w), loP(b.x,b.y), loP(b.z,b.w) };
        int boff = row*1024 + (((col0 + 8*k)*2) ^ ((row & 7) << 4));
        *(uint4*)((char*)hhi_l + boff) = hi4;
        *(uint4*)((char*)hlo_l + boff) = lo4;
      }
    }
    // own-wave LDS writes must land before own-wave A-fragment reads
    asm volatile("s_waitcnt lgkmcnt(0)" ::: "memory");
    __builtin_amdgcn_sched_barrier(0);

    // Phase 2 (per-wave): GEMM on own quarter; wave w owns kt in [4w,4w+4)
    f32x4 acc[3];
    #pragma unroll
    for (int nt = 0; nt < 3; ++nt) acc[nt] = {0.f, 0.f, 0.f, 0.f};
    #pragma unroll
    for (int kk = 0; kk < 4; ++kk){
      int kt = wave*4 + kk;
      int arow = lane & 15;
      int aboff = arow*1024 + ((kt*64 + (lane >> 4)*16) ^ ((arow & 7) << 4));
      bf16x8 ahi = *(const bf16x8*)((const char*)hhi_l + aboff);
      bf16x8 alo = *(const bf16x8*)((const char*)hlo_l + aboff);
      #pragma unroll
      for (int nt = 0; nt < 3; ++nt){
        int bboff = (((nt*16 + kt)*64) + lane)*16;
        bf16x8 bhi = *(const bf16x8*)((const char*)whi_l + bboff);
        bf16x8 blo = *(const bf16x8*)((const char*)wlo_l + bboff);
        acc[nt] = MFMA(ahi, bhi, acc[nt]);
        acc[nt] = MFMA(ahi, blo, acc[nt]);
        acc[nt] = MFMA(alo, bhi, acc[nt]);
      }
    }
    #pragma unroll
    for (int nt = 0; nt < 3; ++nt)
      *(f32x4*)(part_l + ((wave*3 + nt)*64 + lane)*4) = acc[nt];
    __syncthreads();   // join waves: partials complete + full h tile staged
                       // (also the consumption-ordering point for tag safety)

    // Phase 4: gates + state update + immediate tagged publish (no drain)
    {
      int b = tid >> 4, hc = tid & 15;
      int lc = ((b >> 2) << 4) | hc;
      int rc = b & 3;
      float gh[3];
      #pragma unroll
      for (int g = 0; g < 3; ++g){
        float s = 0.f;
        #pragma unroll
        for (int w = 0; w < 4; ++w) s += part_l[((w*3 + g)*64 + lc)*4 + rc];
        gh[g] = s;
      }
      float gi[3];
      #pragma unroll
      for (int g = 0; g < 3; ++g){
        float s = 0.f;
        #pragma unroll
        for (int ii = 0; ii < I_DIM; ++ii)
          s += x_l[b*I_DIM + ii] * wih_l[(g*16 + hc)*I_DIM + ii];
        gi[g] = s;
      }
      float r = fsigmoid(gi[0] + gh[0]);
      float z = fsigmoid(gi[1] + gh[1]);
      float n = ftanh(gi[2] + r*gh[2]);
      int colg = cg*HC + hc;
      int hoff = b*1024 + ((colg*2) ^ ((b & 7) << 4));
      float hp = bf16f(*(unsigned short*)((char*)hhi_l + hoff))
               + bf16f(*(unsigned short*)((char*)hlo_l + hoff));
      float hn = (1.0f - z)*n + z*hp;

      unsigned short shi, slo; split_bf16(hn, shi, slo);
      unsigned int pk = ((unsigned int)shi << 16) | ((unsigned int)slo & 0xFFFCu)
                      | (unsigned int)((t + 1) & 3);
      int gidx = (bg*BB + b)*H_DIM + colg;
      dev_store_u32(hx[nxt] + gidx, pk);     // fire and forget — tag rides along
      if (t == T_STEPS - 1) out[32768 + gidx] = hn;   // h_last
    }

    // logits for step t-1 (after h publication; reads still-staged h_t tile)
    if (cg < 4 && t > 0){
      int o = cg & 1;
      int b = ((cg >> 1) << 3) + (tid >> 5);
      int s = tid & 31;
      float p = 0.f;
      #pragma unroll
      for (int q = 0; q < 2; ++q){
        int c = s*16 + q*8;
        int boff = b*1024 + ((c*2) ^ ((b & 7) << 4));
        uint4 vh = *(const uint4*)((const char*)hhi_l + boff);
        uint4 vl = *(const uint4*)((const char*)hlo_l + boff);
        const unsigned short* ph = (const unsigned short*)&vh;
        const unsigned short* pl = (const unsigned short*)&vl;
        #pragma unroll
        for (int e = 0; e < 8; ++e)
          p += (bf16f(ph[e]) + bf16f(pl[e])) * wpred_l[o*H_DIM + c + e];
      }
      #pragma unroll
      for (int m = 1; m < 32; m <<= 1) p += __shfl_xor(p, m);
      if (s == 0) out[((bg*BB + b)*T_STEPS + (t-1))*2 + o] = p;
    }

    __syncthreads();   // protect hhi_l/hlo_l/x_l before next iteration rewrites
  }

  // ---- epilogue: logits for step 127 from hx[0] (tag 128&3 = 0) ----
  if (cg < 4){
    int row = tid & 15, col0 = (tid >> 4) * 32;
    const unsigned int* p = hx[0] + (bg*BB + row)*H_DIM + col0;
    uint4 pr[8];
    poll_h_row(p, pr, 0u);
    #pragma unroll
    for (int k = 0; k < 4; ++k){
      uint4 a = pr[2*k], b = pr[2*k+1];
      uint4 hi4 = { hiP(a.x,a.y), hiP(a.z,a.w), hiP(b.x,b.y), hiP(b.z,b.w) };
      uint4 lo4 = { loP(a.x,a.y), loP(a.z,a.w), loP(b.x,b.y), loP(b.z,b.w) };
      int boff = row*1024 + (((col0 + 8*k)*2) ^ ((row & 7) << 4));
      *(uint4*)((char*)hhi_l + boff) = hi4;
      *(uint4*)((char*)hlo_l + boff) = lo4;
    }
    __syncthreads();
    int o = cg & 1;
    int b = ((cg >> 1) << 3) + (tid >> 5);
    int s = tid & 31;
    float pacc = 0.f;
    #pragma unroll
    for (int q = 0; q < 2; ++q){
      int c = s*16 + q*8;
      int boff = b*1024 + ((c*2) ^ ((b & 7) << 4));
      uint4 vh = *(const uint4*)((const char*)hhi_l + boff);
      uint4 vl = *(const uint4*)((const char*)hlo_l + boff);
      const unsigned short* ph = (const unsigned short*)&vh;
      const unsigned short* pl = (const unsigned short*)&vl;
      #pragma unroll
      for (int e = 0; e < 8; ++e)
        pacc += (bf16f(ph[e]) + bf16f(pl[e])) * wpred_l[o*H_DIM + c + e];
    }
    #pragma unroll
    for (int m = 1; m < 32; m <<= 1) pacc += __shfl_xor(pacc, m);
    if (s == 0) out[((bg*BB + b)*T_STEPS + 127)*2 + o] = pacc;
  }
}

extern "C" void kernel_launch(void* const* d_in, const int* in_sizes, int n_in,
                              void* d_out, int out_size, void* d_ws, size_t ws_size,
                              hipStream_t stream) {
  const float* hist  = (const float*)d_in[0];   // [128][128][12]
  const float* wih   = (const float*)d_in[1];   // [1536][12]
  const float* whh   = (const float*)d_in[2];   // [1536][512]
  const float* wpred = (const float*)d_in[3];   // [2][512]
  float* out = (float*)d_out;
  unsigned char* ws = (unsigned char*)d_ws;

  // init-barrier flags must start at 0 every call (sc1 write-through -> reliable)
  hipMemsetAsync(ws + WS_FLAGS, 0, 8*CG_N*CG_N*4, stream);

  gru_persistent<<<dim3(256), dim3(NTHREADS), 0, stream>>>(hist, wih, whh, wpred, out, ws);
}

// Round 9
// 524.500 us; speedup vs baseline: 1.1859x; 1.1859x over previous
//
#include <hip/hip_runtime.h>
#include <cstdint>

// GRU (B=128, T=128, I=12, H=512) persistent kernel, round 9.
// 256 WGs = 8 batch-groups (16 rows) x 32 col-groups (16 h-cols), 1 WG/CU.
// W_hh chunk LDS-resident in MFMA fragment order (bf16 hi/lo x3 MFMA).
// Base = round 7 (601us): self-tagged exchange (u32 = hi16|lo14|tag2), sc1,
// no per-step flags. Round-9:
//  (a) trailing __syncthreads -> RAW s_barrier: no vmcnt(0) drain of the
//      publish stores (their ack was serializing ~1 fabric RT every step).
//      Safe: same-slot republish always separated by next poll's vmcnt(0);
//      consumers self-validate via tags; no LDS ops outstanding at barrier.
//  (b) stage/mid barriers -> lgkmcnt(0) + raw s_barrier (LDS-only drain).
//  (c) logits spread uniformly: every WG's wave0 does ONE (row,output) dot
//      per step (was cg<4 doing 8x the work -> per-step straggler skew).

typedef __attribute__((ext_vector_type(4))) float f32x4;
typedef __attribute__((ext_vector_type(8))) __bf16 bf16x8;

#define NTHREADS 256
#define CG_N 32
#define BB 16
#define HC 16
#define T_STEPS 128
#define I_DIM 12
#define H_DIM 512

// ws byte offsets
#define WS_HX0   0         // hx[0]: [128][512] u32   256 KB
#define WS_HX1   262144    // hx[1]                   256 KB
#define WS_FLAGS 524288    // [8 bg][32 consumer][32 producer] u32 (init barrier only)

__device__ __forceinline__ float bf16f(unsigned short u){
  return __uint_as_float(((unsigned int)u) << 16);
}
__device__ __forceinline__ void split_bf16(float x, unsigned short &hi, unsigned short &lo){
  unsigned int u = __float_as_uint(x);
  hi = (unsigned short)(u >> 16);
  float r = x - __uint_as_float((u >> 16) << 16);   // exact residual
  unsigned int ru = __float_as_uint(r);
  ru += 0x7fffu + ((ru >> 16) & 1u);                // RNE to bf16
  lo = (unsigned short)(ru >> 16);
}
__device__ __forceinline__ float fsigmoid(float x){ return 1.0f / (1.0f + __expf(-x)); }
__device__ __forceinline__ float ftanh(float x){ return 2.0f / (1.0f + __expf(-2.0f * x)) - 1.0f; }
__device__ __forceinline__ f32x4 MFMA(bf16x8 a, bf16x8 b, f32x4 c){
  return __builtin_amdgcn_mfma_f32_16x16x32_bf16(a, b, c, 0, 0, 0);
}
__device__ __forceinline__ void wait_vm0(){
  asm volatile("s_waitcnt vmcnt(0)" ::: "memory");
}
__device__ __forceinline__ unsigned int hiP(unsigned int x, unsigned int y){
  return (x >> 16) | (y & 0xFFFF0000u);
}
__device__ __forceinline__ unsigned int loP(unsigned int x, unsigned int y){
  return (x & 0xFFFFu) | (y << 16);
}

// raw barriers (HK pattern): sched_barrier fences pin ordering; no waitcnt
__device__ __forceinline__ void bar_lgkm(){
  asm volatile("s_waitcnt lgkmcnt(0)" ::: "memory");
  __builtin_amdgcn_sched_barrier(0);
  __builtin_amdgcn_s_barrier();
  __builtin_amdgcn_sched_barrier(0);
}
__device__ __forceinline__ void bar_raw(){
  __builtin_amdgcn_sched_barrier(0);
  __builtin_amdgcn_s_barrier();
  __builtin_amdgcn_sched_barrier(0);
}

// sc1 (device-scope) primitives — proven r3/r4/r7 exchange path
__device__ __forceinline__ void dev_store_u32(unsigned int* p, unsigned int v){
  asm volatile("global_store_dword %0, %1, off sc1" :: "v"(p), "v"(v) : "memory");
}
__device__ __forceinline__ unsigned int dev_load_u32(const unsigned int* p){
  unsigned int v;
  asm volatile("global_load_dword %0, %1, off sc1\n\ts_waitcnt vmcnt(0)"
               : "=v"(v) : "v"(p) : "memory");
  return v;
}
__device__ __forceinline__ uint4 load4_sc1(const unsigned int* p){
  uint4 v;
  asm volatile("global_load_dwordx4 %0, %1, off sc1" : "=v"(v) : "v"(p) : "memory");
  return v;
}
__device__ __forceinline__ void load_h_row(const unsigned int* p, uint4* pr){
  uint4 v0, v1, v2, v3, v4, v5, v6, v7;
  asm volatile(
    "global_load_dwordx4 %0, %8, off sc1\n\t"
    "global_load_dwordx4 %1, %8, off offset:16 sc1\n\t"
    "global_load_dwordx4 %2, %8, off offset:32 sc1\n\t"
    "global_load_dwordx4 %3, %8, off offset:48 sc1\n\t"
    "global_load_dwordx4 %4, %8, off offset:64 sc1\n\t"
    "global_load_dwordx4 %5, %8, off offset:80 sc1\n\t"
    "global_load_dwordx4 %6, %8, off offset:96 sc1\n\t"
    "global_load_dwordx4 %7, %8, off offset:112 sc1\n\t"
    "s_waitcnt vmcnt(0)"
    : "=&v"(v0), "=&v"(v1), "=&v"(v2), "=&v"(v3),
      "=&v"(v4), "=&v"(v5), "=&v"(v6), "=&v"(v7)
    : "v"(p) : "memory");
  pr[0]=v0; pr[1]=v1; pr[2]=v2; pr[3]=v3; pr[4]=v4; pr[5]=v5; pr[6]=v6; pr[7]=v7;
}

// r7-style poll: full re-sweep until all 32 u32 carry tag `want`, then mask
__device__ __forceinline__ void poll_h_row(const unsigned int* p, uint4* pr,
                                           unsigned int want){
  for (;;){
    load_h_row(p, pr);
    unsigned int diff = 0u;
    #pragma unroll
    for (int b = 0; b < 8; ++b)
      diff |= (pr[b].x ^ want) | (pr[b].y ^ want) | (pr[b].z ^ want) | (pr[b].w ^ want);
    if ((diff & 3u) == 0u) break;
  }
  #pragma unroll
  for (int b = 0; b < 8; ++b){
    pr[b].x &= 0xFFFFFFFCu; pr[b].y &= 0xFFFFFFFCu;
    pr[b].z &= 0xFFFFFFFCu; pr[b].w &= 0xFFFFFFFCu;
  }
}

extern "C" __global__ void __launch_bounds__(NTHREADS, 1)
gru_persistent(const float* __restrict__ hist, const float* __restrict__ wih,
               const float* __restrict__ whh, const float* __restrict__ wpred,
               float* __restrict__ out, unsigned char* __restrict__ ws)
{
  __shared__ __align__(16) unsigned short whi_l[3*16*64*8];   // 49152 B
  __shared__ __align__(16) unsigned short wlo_l[3*16*64*8];   // 49152 B
  __shared__ __align__(16) unsigned short hhi_l[BB*H_DIM];    // 16384 B (swizzled)
  __shared__ __align__(16) unsigned short hlo_l[BB*H_DIM];    // 16384 B (swizzled)
  __shared__ __align__(16) float part_l[4*3*64*4];            // 12288 B
  __shared__ __align__(16) float x_l[BB*I_DIM];               // 768 B
  __shared__ __align__(16) float wih_l[48*I_DIM];             // 2304 B
  __shared__ __align__(16) float wpred_l[2*H_DIM];            // 4096 B

  const int tid  = threadIdx.x;
  const int bg   = blockIdx.x & 7;
  const int cg   = blockIdx.x >> 3;
  const int wave = tid >> 6;
  const int lane = tid & 63;
  const int b_log = cg & 15;       // this WG's logit row
  const int o_log = cg >> 4;       // this WG's logit output

  unsigned int* hx[2] = {(unsigned int*)(ws + WS_HX0), (unsigned int*)(ws + WS_HX1)};
  unsigned int* flagsP = (unsigned int*)(ws + WS_FLAGS);

  // ---- Prologue: stage W_ih / W_pred, convert W_hh chunk to LDS fragments ----
  for (int i = tid; i < 48*I_DIM; i += NTHREADS){
    int j = i / I_DIM, ii = i % I_DIM;
    int R = (j >> 4)*H_DIM + cg*HC + (j & 15);      // gate-major rows: r,z,n
    wih_l[i] = wih[R*I_DIM + ii];
  }
  for (int i = tid; i < 2*H_DIM; i += NTHREADS) wpred_l[i] = wpred[i];
  #pragma unroll
  for (int it = 0; it < 24; ++it){
    int f0 = (it*NTHREADS + tid) * 4;               // flat [48*512], k-aligned 4
    int j = f0 >> 9, k = f0 & 511;
    int R = (j >> 4)*H_DIM + cg*HC + (j & 15);
    float4 v = *(const float4*)(whh + R*H_DIM + k);
    int nt = j >> 4;
    int ln = (j & 15) | (((k >> 3) & 3) << 4);
    int kt = k >> 5, e = k & 7;
    int base = (((nt*16 + kt)*64) + ln)*8 + e;      // half index
    float vv[4] = {v.x, v.y, v.z, v.w};
    unsigned short h4[4], l4[4];
    #pragma unroll
    for (int q = 0; q < 4; ++q) split_bf16(vv[q], h4[q], l4[q]);
    uint2 uh, ul;
    uh.x = (unsigned int)h4[0] | ((unsigned int)h4[1] << 16);
    uh.y = (unsigned int)h4[2] | ((unsigned int)h4[3] << 16);
    ul.x = (unsigned int)l4[0] | ((unsigned int)l4[1] << 16);
    ul.y = (unsigned int)l4[2] | ((unsigned int)l4[3] << 16);
    *(uint2*)((char*)whi_l + base*2) = uh;
    *(uint2*)((char*)wlo_l + base*2) = ul;
  }

  // ---- init: rewrite BOTH slots (erase replay-stale tags), then one
  //      sc1 flag barrier (prevents step-0 stale-tag-0 reads). ----
  {
    int b = tid >> 4, hc = tid & 15;
    int gidx = (bg*BB + b)*H_DIM + cg*HC + hc;
    dev_store_u32(hx[0] + gidx, 0u);   // h0=0, tag=0
    dev_store_u32(hx[1] + gidx, 2u);   // payload irrelevant, tag=2
  }
  wait_vm0();
  __syncthreads();
  if (wave == 0 && lane < CG_N)
    dev_store_u32(flagsP + (bg*CG_N + lane)*CG_N + cg, 1u);
  if (wave == 0){
    const unsigned int* fp = flagsP + (bg*CG_N + cg)*CG_N + (lane & 31);
    for (;;){
      unsigned int f = dev_load_u32(fp);
      if (__ballot(f >= 1u) == ~0ull) break;
      __builtin_amdgcn_s_sleep(1);
    }
  }
  __syncthreads();

  // ---- main recurrence: tag-gated dataflow, NO vmem drains at barriers ----
  for (int t = 0; t < T_STEPS; ++t){
    const int cur = t & 1, nxt = cur ^ 1;

    if (tid < BB*I_DIM){
      int b = tid / I_DIM, ii = tid % I_DIM;
      x_l[tid] = hist[((bg*BB + b)*T_STEPS + t)*I_DIM + ii];
    }

    // Phase 1: poll self-tagged h -> unpack -> swizzled LDS
    {
      int row = tid & 15, col0 = (tid >> 4) * 32;
      const unsigned int* p = hx[cur] + (bg*BB + row)*H_DIM + col0;
      uint4 pr[8];
      poll_h_row(p, pr, (unsigned int)(t & 3));
      #pragma unroll
      for (int k = 0; k < 4; ++k){
        uint4 a = pr[2*k], b = pr[2*k+1];
        uint4 hi4 = { hiP(a.x,a.y), hiP(a.z,a.w), hiP(b.x,b.y), hiP(b.z,b.w) };
        uint4 lo4 = { loP(a.x,a.y), loP(a.z,a.w), loP(b.x,b.y), loP(b.z,b.w) };
        int boff = row*1024 + (((col0 + 8*k)*2) ^ ((row & 7) << 4));
        *(uint4*)((char*)hhi_l + boff) = hi4;
        *(uint4*)((char*)hlo_l + boff) = lo4;
      }
    }
    bar_lgkm();   // h tile + x staged, LDS visible; NO vmem drain

    // Phase 2: GEMM; wave w owns kt in [4w, 4w+4)
    f32x4 acc[3];
    #pragma unroll
    for (int nt = 0; nt < 3; ++nt) acc[nt] = {0.f, 0.f, 0.f, 0.f};
    #pragma unroll
    for (int kk = 0; kk < 4; ++kk){
      int kt = wave*4 + kk;
      int arow = lane & 15;
      int aboff = arow*1024 + ((kt*64 + (lane >> 4)*16) ^ ((arow & 7) << 4));
      bf16x8 ahi = *(const bf16x8*)((const char*)hhi_l + aboff);
      bf16x8 alo = *(const bf16x8*)((const char*)hlo_l + aboff);
      #pragma unroll
      for (int nt = 0; nt < 3; ++nt){
        int bboff = (((nt*16 + kt)*64) + lane)*16;
        bf16x8 bhi = *(const bf16x8*)((const char*)whi_l + bboff);
        bf16x8 blo = *(const bf16x8*)((const char*)wlo_l + bboff);
        acc[nt] = MFMA(ahi, bhi, acc[nt]);
        acc[nt] = MFMA(ahi, blo, acc[nt]);
        acc[nt] = MFMA(alo, bhi, acc[nt]);
      }
    }
    #pragma unroll
    for (int nt = 0; nt < 3; ++nt)
      *(f32x4*)(part_l + ((wave*3 + nt)*64 + lane)*4) = acc[nt];
    bar_lgkm();   // partials visible; NO vmem drain

    // Phase 4: gates + state update + immediate tagged publish (no drain)
    {
      int b = tid >> 4, hc = tid & 15;
      int lc = ((b >> 2) << 4) | hc;
      int rc = b & 3;
      float gh[3];
      #pragma unroll
      for (int g = 0; g < 3; ++g){
        float s = 0.f;
        #pragma unroll
        for (int w = 0; w < 4; ++w) s += part_l[((w*3 + g)*64 + lc)*4 + rc];
        gh[g] = s;
      }
      float gi[3];
      #pragma unroll
      for (int g = 0; g < 3; ++g){
        float s = 0.f;
        #pragma unroll
        for (int ii = 0; ii < I_DIM; ++ii)
          s += x_l[b*I_DIM + ii] * wih_l[(g*16 + hc)*I_DIM + ii];
        gi[g] = s;
      }
      float r = fsigmoid(gi[0] + gh[0]);
      float z = fsigmoid(gi[1] + gh[1]);
      float n = ftanh(gi[2] + r*gh[2]);
      int colg = cg*HC + hc;
      int hoff = b*1024 + ((colg*2) ^ ((b & 7) << 4));
      float hp = bf16f(*(unsigned short*)((char*)hhi_l + hoff))
               + bf16f(*(unsigned short*)((char*)hlo_l + hoff));
      float hn = (1.0f - z)*n + z*hp;

      unsigned short shi, slo; split_bf16(hn, shi, slo);
      unsigned int pk = ((unsigned int)shi << 16) | ((unsigned int)slo & 0xFFFCu)
                      | (unsigned int)((t + 1) & 3);
      int gidx = (bg*BB + b)*H_DIM + colg;
      dev_store_u32(hx[nxt] + gidx, pk);     // fire and forget — tag rides along
      if (t == T_STEPS - 1) out[32768 + gidx] = hn;   // h_last
    }

    // logits for step t-1: uniform spread — wave0 of EVERY WG does one
    // (row=b_log, output=o_log) dot from the still-staged h_t tile.
    if (wave == 0 && t > 0){
      int c = lane * 8;
      int boff = b_log*1024 + ((c*2) ^ ((b_log & 7) << 4));
      uint4 vh = *(const uint4*)((const char*)hhi_l + boff);
      uint4 vl = *(const uint4*)((const char*)hlo_l + boff);
      const unsigned short* ph = (const unsigned short*)&vh;
      const unsigned short* pl = (const unsigned short*)&vl;
      float p = 0.f;
      #pragma unroll
      for (int e = 0; e < 8; ++e)
        p += (bf16f(ph[e]) + bf16f(pl[e])) * wpred_l[o_log*H_DIM + c + e];
      #pragma unroll
      for (int m = 1; m < 64; m <<= 1) p += __shfl_xor(p, m);
      if (lane == 0) out[((bg*BB + b_log)*T_STEPS + (t-1))*2 + o_log] = p;
    }

    bar_raw();   // protect LDS tiles; publish stores stay IN FLIGHT
  }

  // ---- epilogue: logits for step 127 from hx[0] (tag 128&3 = 0), wave0 ----
  if (wave == 0){
    const unsigned int* p = hx[0] + (bg*BB + b_log)*H_DIM + lane*8;
    uint4 a0, a1;
    for (;;){
      a0 = load4_sc1(p); a1 = load4_sc1(p + 4);
      wait_vm0();
      unsigned int diff = (a0.x | a0.y | a0.z | a0.w | a1.x | a1.y | a1.z | a1.w);
      // tags must all be 0: OR of tag bits == 0
      if ((((a0.x ^ 0u) | (a0.y) | (a0.z) | (a0.w) | a1.x | a1.y | a1.z | a1.w) & 3u) == 0u) break;
      (void)diff;
      __builtin_amdgcn_s_sleep(1);
    }
    const unsigned int pk8[8] = {a0.x & 0xFFFFFFFCu, a0.y & 0xFFFFFFFCu,
                                 a0.z & 0xFFFFFFFCu, a0.w & 0xFFFFFFFCu,
                                 a1.x & 0xFFFFFFFCu, a1.y & 0xFFFFFFFCu,
                                 a1.z & 0xFFFFFFFCu, a1.w & 0xFFFFFFFCu};
    float pacc = 0.f;
    #pragma unroll
    for (int e = 0; e < 8; ++e){
      unsigned int v = pk8[e];
      float hv = bf16f((unsigned short)(v >> 16)) + bf16f((unsigned short)(v & 0xFFFFu));
      pacc += hv * wpred_l[o_log*H_DIM + lane*8 + e];
    }
    #pragma unroll
    for (int m = 1; m < 64; m <<= 1) pacc += __shfl_xor(pacc, m);
    if (lane == 0) out[((bg*BB + b_log)*T_STEPS + 127)*2 + o_log] = pacc;
  }
}

extern "C" void kernel_launch(void* const* d_in, const int* in_sizes, int n_in,
                              void* d_out, int out_size, void* d_ws, size_t ws_size,
                              hipStream_t stream) {
  const float* hist  = (const float*)d_in[0];   // [128][128][12]
  const float* wih   = (const float*)d_in[1];   // [1536][12]
  const float* whh   = (const float*)d_in[2];   // [1536][512]
  const float* wpred = (const float*)d_in[3];   // [2][512]
  float* out = (float*)d_out;
  unsigned char* ws = (unsigned char*)d_ws;

  // init-barrier flags must start at 0 every call (sc1 write-through -> reliable)
  hipMemsetAsync(ws + WS_FLAGS, 0, 8*CG_N*CG_N*4, stream);

  gru_persistent<<<dim3(256), dim3(NTHREADS), 0, stream>>>(hist, wih, whh, wpred, out, ws);
}